// Round 4
// 140.713 us; speedup vs baseline: 1.0540x; 1.0540x over previous
//
#include <hip/hip_runtime.h>
#include <math.h>

#define EPS_F 1e-6f

// ---- workspace layout (float offsets) ----
#define OFF_WCQ 0                            // folded q weights [256][256]
#define OFF_WCK (OFF_WCQ + 65536)            // folded k weights [256][256]
#define OFF_BV  (OFF_WCK + 65536)            // folded v bias [256]
#define OFF_VC  (OFF_BV + 256)               // dwconv output [256][4096]
#define OFF_PS  (OFF_VC + 256*4096)          // partial Sm [8 h][64 chunk][64][64]
#define OFF_PSV (OFF_PS + 8*64*4096)         // partial sv [8 h][64 chunk][64]
#define OFF_SM  (OFF_PSV + 8*64*64)          // Sm [8][64*64]
#define OFF_SV  (OFF_SM + 8*4096)            // sv [8][64]
#define OFF_QF  (OFF_SV + 512)               // qf features [8 h][64 a][4096 n]

// Fold hedgehog linear into 1x1x1 conv: Wcq[h*64+e,c] = sum_d Wmq[e,d]*Wq[h*64+d,c]
__global__ __launch_bounds__(256) void k_combine(
    const float* __restrict__ Wq, const float* __restrict__ Wk,
    const float* __restrict__ Wmq, const float* __restrict__ Wmk,
    const float* __restrict__ Wmv, const float* __restrict__ bmv,
    const float* __restrict__ bv, float* __restrict__ ws)
{
    int row = blockIdx.x;        // h*64+e
    int c = threadIdx.x;
    int h = row >> 6, e = row & 63;
    float aq = 0.f, ak = 0.f;
    for (int d = 0; d < 64; ++d) {
        float mq = Wmq[e*64 + d];
        float mk = Wmk[e*64 + d];
        int src = (h*64 + d)*256 + c;
        aq = fmaf(mq, Wq[src], aq);
        ak = fmaf(mk, Wk[src], ak);
    }
    ws[OFF_WCQ + row*256 + c] = aq;
    ws[OFF_WCK + row*256 + c] = ak;
    if (c == 0) {
        float av = 0.f;
        for (int d = 0; d < 64; ++d) av = fmaf(Wmv[e*64 + d], bv[h*64 + d], av);
        ws[OFF_BV + row] = av + bmv[e];
    }
}

// depthwise 3x3x3 conv, zero pad
__global__ __launch_bounds__(256) void k_dwconv(
    const float* __restrict__ x, const float* __restrict__ Wv, float* __restrict__ vc)
{
    int c = blockIdx.y;
    int n = blockIdx.x * 256 + threadIdx.x;
    int z = n >> 8, y = (n >> 4) & 15, xx = n & 15;
    const float* xc = x + c * 4096;
    const float* wc = Wv + c * 27;
    float acc = 0.f;
    #pragma unroll
    for (int kz = 0; kz < 3; ++kz) {
        int zz = z + kz - 1;
        if (zz < 0 || zz > 15) continue;
        #pragma unroll
        for (int ky = 0; ky < 3; ++ky) {
            int yy = y + ky - 1;
            if (yy < 0 || yy > 15) continue;
            #pragma unroll
            for (int kx = 0; kx < 3; ++kx) {
                int xv = xx + kx - 1;
                if (xv < 0 || xv > 15) continue;
                acc = fmaf(wc[(kz*3 + ky)*3 + kx], xc[(zz << 8) + (yy << 4) + xv], acc);
            }
        }
    }
    vc[c*4096 + n] = acc;
}

// 512 threads: waves 0-3 ("K group", t<256) do K-proj (K=256) + V-proj (K=64),
// waves 4-7 ("Q group", t>=256) do Q-proj (K=256) sharing the staged X tile and
// write exp(+-q) to global qf. Phase 3 (outer products) is n-split across both
// groups with an LDS exchange reduction.
__global__ __launch_bounds__(512, 2) void k_fused(
    const float* __restrict__ X, const float* __restrict__ bmk,
    const float* __restrict__ bmq, const float* __restrict__ Wmv,
    float* __restrict__ ws)
{
    __shared__ float smem[16384];   // 64 KB
    float (*Xs)[64]  = (float(*)[64])smem;            // phase 1: 4096
    float (*Wsk)[68] = (float(*)[68])(smem + 4096);   // phase 1: 4352
    float (*Wsq)[68] = (float(*)[68])(smem + 8448);   // phase 1: 4352
    float (*kfp)[64] = (float(*)[64])smem;            // phase 2/3
    float (*kfm)[64] = (float(*)[64])(smem + 4096);
    float (*vfp)[64] = (float(*)[64])(smem + 8192);
    float (*vfm)[64] = (float(*)[64])(smem + 12288);

    int t = threadIdx.x;
    int chunk = blockIdx.x;       // 0..63
    int hb = blockIdx.y;          // 0..3
    int n0 = chunk * 64;
    bool isQ = (t >= 256);        // wave-uniform
    int tl = t & 255;
    int lc = tl >> 6, ln = tl & 63;
    int e4 = (tl & 15) * 4;
    int n4 = (tl >> 4) * 4;

    float acc[4][4];              // K group: accK; Q group: accQ
    float accV[4][4];
    #pragma unroll
    for (int i = 0; i < 4; ++i)
        #pragma unroll
        for (int j = 0; j < 4; ++j) { acc[i][j] = 0.f; accV[i][j] = 0.f; }

    // ---- phase 1: K/Q projection GEMMs, K=256, shared X staging ----
    const float* Wck = ws + OFF_WCK;
    const float* Wcq = ws + OFF_WCQ;
    for (int c0 = 0; c0 < 256; c0 += 64) {
        if (!isQ) {
            #pragma unroll
            for (int i = 0; i < 16; ++i)
                Xs[lc*16 + i][ln] = X[(size_t)(c0 + lc*16 + i)*4096 + n0 + ln];
        } else {
            #pragma unroll
            for (int i = 0; i < 16; ++i) {
                Wsk[ln][lc*16 + i] = Wck[(size_t)(hb*64 + lc*16 + i)*256 + c0 + ln];
                Wsq[ln][lc*16 + i] = Wcq[(size_t)(hb*64 + lc*16 + i)*256 + c0 + ln];
            }
        }
        __syncthreads();
        const float (*Wsh)[68] = isQ ? (const float (*)[68])Wsq : (const float (*)[68])Wsk;
        #pragma unroll 4
        for (int c = 0; c < 64; ++c) {
            float4 xv4 = *(const float4*)&Xs[c][n4];
            float4 wv4 = *(const float4*)&Wsh[c][e4];
            float xv[4] = {xv4.x, xv4.y, xv4.z, xv4.w};
            float wv[4] = {wv4.x, wv4.y, wv4.z, wv4.w};
            #pragma unroll
            for (int ii = 0; ii < 4; ++ii)
                #pragma unroll
                for (int jj = 0; jj < 4; ++jj)
                    acc[ii][jj] = fmaf(xv[ii], wv[jj], acc[ii][jj]);
        }
        __syncthreads();
    }

    // ---- K group: stage V tiles.  Q group: exp(+-q) -> global qf ----
    if (!isQ) {
        const float* vcb = ws + OFF_VC + (size_t)hb*64*4096;
        #pragma unroll
        for (int i = 0; i < 16; ++i)
            Xs[lc*16 + i][ln] = vcb[(size_t)(lc*16 + i)*4096 + n0 + ln];
        #pragma unroll
        for (int i = 0; i < 16; ++i) { int idx = i*256 + tl; Wsk[idx & 63][idx >> 6] = Wmv[idx]; }
    } else {
        float* gq = ws + OFF_QF;
        #pragma unroll
        for (int jj = 0; jj < 4; ++jj) {
            float b = bmq[e4 + jj];
            float a0 = acc[0][jj] + b, a1 = acc[1][jj] + b,
                  a2 = acc[2][jj] + b, a3 = acc[3][jj] + b;
            *(float4*)&gq[(size_t)(hb*64 + e4 + jj)*4096 + n0 + n4] =
                make_float4(__expf(a0), __expf(a1), __expf(a2), __expf(a3));
            *(float4*)&gq[(size_t)((hb + 4)*64 + e4 + jj)*4096 + n0 + n4] =
                make_float4(__expf(-a0), __expf(-a1), __expf(-a2), __expf(-a3));
        }
    }
    __syncthreads();

    // ---- V-projection GEMM (K group only), K=64 ----
    if (!isQ) {
        #pragma unroll 4
        for (int d = 0; d < 64; ++d) {
            float4 xv4 = *(const float4*)&Xs[d][n4];
            float4 wv4 = *(const float4*)&Wsk[d][e4];
            float xv[4] = {xv4.x, xv4.y, xv4.z, xv4.w};
            float wv[4] = {wv4.x, wv4.y, wv4.z, wv4.w};
            #pragma unroll
            for (int ii = 0; ii < 4; ++ii)
                #pragma unroll
                for (int jj = 0; jj < 4; ++jj)
                    accV[ii][jj] = fmaf(xv[ii], wv[jj], accV[ii][jj]);
        }
    }
    __syncthreads();

    // ---- phase 2: bias + exp+- for k,v into LDS [n][a] (K group) ----
    if (!isQ) {
        float bk[4], bvv[4];
        #pragma unroll
        for (int j = 0; j < 4; ++j) { bk[j] = bmk[e4 + j]; bvv[j] = ws[OFF_BV + hb*64 + e4 + j]; }
        #pragma unroll
        for (int ii = 0; ii < 4; ++ii) {
            float pk[4], mk_[4], pv[4], mv[4];
            #pragma unroll
            for (int jj = 0; jj < 4; ++jj) {
                float a = acc[ii][jj] + bk[jj];
                pk[jj] = __expf(a);  mk_[jj] = __expf(-a);
                float b = accV[ii][jj] + bvv[jj];
                pv[jj] = __expf(b);  mv[jj] = __expf(-b);
            }
            *(float4*)&kfp[n4 + ii][e4] = make_float4(pk[0], pk[1], pk[2], pk[3]);
            *(float4*)&kfm[n4 + ii][e4] = make_float4(mk_[0], mk_[1], mk_[2], mk_[3]);
            *(float4*)&vfp[n4 + ii][e4] = make_float4(pv[0], pv[1], pv[2], pv[3]);
            *(float4*)&vfm[n4 + ii][e4] = make_float4(mv[0], mv[1], mv[2], mv[3]);
        }
    }
    __syncthreads();

    // ---- phase 3: outer products, n-split across groups ----
    float aSp[4][4], aSm[4][4], svp[4], svm[4];
    #pragma unroll
    for (int i = 0; i < 4; ++i) {
        svp[i] = 0.f; svm[i] = 0.f;
        #pragma unroll
        for (int j = 0; j < 4; ++j) { aSp[i][j] = 0.f; aSm[i][j] = 0.f; }
    }
    int a4 = e4, f4 = n4;
    int nb = isQ ? 32 : 0;
    #pragma unroll 2
    for (int nn = 0; nn < 32; ++nn) {
        int n = nb + nn;
        float4 kp4 = *(const float4*)&kfp[n][a4];
        float4 km4 = *(const float4*)&kfm[n][a4];
        float4 vp4 = *(const float4*)&vfp[n][f4];
        float4 vm4 = *(const float4*)&vfm[n][f4];
        float kp[4] = {kp4.x, kp4.y, kp4.z, kp4.w};
        float km[4] = {km4.x, km4.y, km4.z, km4.w};
        float vp[4] = {vp4.x, vp4.y, vp4.z, vp4.w};
        float vm[4] = {vm4.x, vm4.y, vm4.z, vm4.w};
        #pragma unroll
        for (int ai = 0; ai < 4; ++ai) {
            svp[ai] += kp[ai];  svm[ai] += km[ai];
            #pragma unroll
            for (int fi = 0; fi < 4; ++fi) {
                aSp[ai][fi] = fmaf(kp[ai], vp[fi], aSp[ai][fi]);
                aSm[ai][fi] = fmaf(km[ai], vm[fi], aSm[ai][fi]);
            }
        }
    }
    __syncthreads();

    // ---- exchange: Q group dumps partials (interleaved, conflict-free), K group adds ----
    if (isQ) {
        #pragma unroll
        for (int i = 0; i < 4; ++i)
            #pragma unroll
            for (int j = 0; j < 4; ++j) {
                smem[(i*4 + j)*256 + tl]        = aSp[i][j];
                smem[(16 + i*4 + j)*256 + tl]   = aSm[i][j];
            }
        if (tl < 16) {
            #pragma unroll
            for (int i = 0; i < 4; ++i) {
                smem[8192 + i*16 + tl]      = svp[i];
                smem[8192 + 64 + i*16 + tl] = svm[i];
            }
        }
    }
    __syncthreads();
    if (!isQ) {
        #pragma unroll
        for (int i = 0; i < 4; ++i)
            #pragma unroll
            for (int j = 0; j < 4; ++j) {
                aSp[i][j] += smem[(i*4 + j)*256 + tl];
                aSm[i][j] += smem[(16 + i*4 + j)*256 + tl];
            }
        float* pSp = ws + OFF_PS + (size_t)(hb*64 + chunk)*4096;
        float* pSm = ws + OFF_PS + (size_t)((hb + 4)*64 + chunk)*4096;
        #pragma unroll
        for (int ai = 0; ai < 4; ++ai) {
            *(float4*)&pSp[(a4 + ai)*64 + f4] = make_float4(aSp[ai][0], aSp[ai][1], aSp[ai][2], aSp[ai][3]);
            *(float4*)&pSm[(a4 + ai)*64 + f4] = make_float4(aSm[ai][0], aSm[ai][1], aSm[ai][2], aSm[ai][3]);
        }
        if (tl < 16) {
            #pragma unroll
            for (int i = 0; i < 4; ++i) {
                svp[i] += smem[8192 + i*16 + tl];
                svm[i] += smem[8192 + 64 + i*16 + tl];
            }
            float* pvp = ws + OFF_PSV + (size_t)(hb*64 + chunk)*64;
            float* pvm = ws + OFF_PSV + (size_t)((hb + 4)*64 + chunk)*64;
            *(float4*)&pvp[a4] = make_float4(svp[0], svp[1], svp[2], svp[3]);
            *(float4*)&pvm[a4] = make_float4(svm[0], svm[1], svm[2], svm[3]);
        }
    }
}

__global__ __launch_bounds__(256) void k_reduce(float* __restrict__ ws)
{
    int idx = blockIdx.x*256 + threadIdx.x;
    if (idx < 8*4096) {
        int h = idx >> 12, r = idx & 4095;
        float s = 0.f;
        #pragma unroll 16
        for (int c = 0; c < 64; ++c) s += ws[OFF_PS + (size_t)(h*64 + c)*4096 + r];
        ws[OFF_SM + idx] = s;
    } else if (idx < 8*4096 + 512) {
        int j = idx - 8*4096;
        int h = j >> 6, e = j & 63;
        float s = 0.f;
        #pragma unroll 16
        for (int c = 0; c < 64; ++c) s += ws[OFF_PSV + (size_t)(h*64 + c)*64 + e];
        ws[OFF_SV + j] = s;
    }
}

// Per (h 0..7, chunk 0..63): out[h] = (qf[h] . Sm[h]) / (qf[h] . sv[h] + eps)
// 512 blocks -> 2 blocks/CU.
__global__ __launch_bounds__(256, 2) void k_out(
    const float* __restrict__ ws, float* __restrict__ out)
{
    __shared__ float qs[64][64];    // qf tile [a][n]
    __shared__ float Sms[64][64];   // Sm[h]   [a][f]
    __shared__ float svs[64];
    int t = threadIdx.x;
    int chunk = blockIdx.x;
    int h = blockIdx.y;
    int n0 = chunk * 64;
    int lc = t >> 6, ln = t & 63;

    const float* gq = ws + OFF_QF + (size_t)h*64*4096;
    #pragma unroll
    for (int i = 0; i < 16; ++i)
        qs[lc*16 + i][ln] = gq[(size_t)(lc*16 + i)*4096 + n0 + ln];
    const float* Smg = ws + OFF_SM + (size_t)h*4096;
    #pragma unroll
    for (int i = 0; i < 16; ++i) { int idx = i*256 + t; Sms[idx >> 6][idx & 63] = Smg[idx]; }
    if (t < 64) svs[t] = ws[OFF_SV + h*64 + t];
    __syncthreads();

    int n4 = (t & 15) * 4;
    int e4 = (t >> 4) * 4;
    float acc[4][4];                // [f][n]
    float den[4] = {0.f, 0.f, 0.f, 0.f};
    #pragma unroll
    for (int i = 0; i < 4; ++i)
        #pragma unroll
        for (int j = 0; j < 4; ++j) acc[i][j] = 0.f;
    #pragma unroll 4
    for (int a = 0; a < 64; ++a) {
        float4 qv4 = *(const float4*)&qs[a][n4];
        float4 sm4 = *(const float4*)&Sms[a][e4];
        float qv[4] = {qv4.x, qv4.y, qv4.z, qv4.w};
        float sm[4] = {sm4.x, sm4.y, sm4.z, sm4.w};
        float sva = svs[a];
        #pragma unroll
        for (int nj = 0; nj < 4; ++nj) {
            den[nj] = fmaf(qv[nj], sva, den[nj]);
            #pragma unroll
            for (int ei = 0; ei < 4; ++ei)
                acc[ei][nj] = fmaf(sm[ei], qv[nj], acc[ei][nj]);
        }
    }
    float r[4];
    #pragma unroll
    for (int nj = 0; nj < 4; ++nj) r[nj] = 1.f / (den[nj] + EPS_F);
    #pragma unroll
    for (int ei = 0; ei < 4; ++ei)
        *(float4*)&out[(size_t)(h*64 + e4 + ei)*4096 + n0 + n4] =
            make_float4(acc[ei][0]*r[0], acc[ei][1]*r[1], acc[ei][2]*r[2], acc[ei][3]*r[3]);
}

extern "C" void kernel_launch(void* const* d_in, const int* in_sizes, int n_in,
                              void* d_out, int out_size, void* d_ws, size_t ws_size,
                              hipStream_t stream) {
    const float* x   = (const float*)d_in[0];
    const float* Wq  = (const float*)d_in[1];
    const float* Wk  = (const float*)d_in[2];
    const float* Wv  = (const float*)d_in[3];
    const float* bv  = (const float*)d_in[4];
    const float* Wmq = (const float*)d_in[5];
    const float* bmq = (const float*)d_in[6];
    const float* Wmk = (const float*)d_in[7];
    const float* bmk = (const float*)d_in[8];
    const float* Wmv = (const float*)d_in[9];
    const float* bmv = (const float*)d_in[10];
    float* out = (float*)d_out;
    float* ws  = (float*)d_ws;

    k_combine<<<256, 256, 0, stream>>>(Wq, Wk, Wmq, Wmk, Wmv, bmv, bv, ws);
    k_dwconv<<<dim3(16, 256), 256, 0, stream>>>(x, Wv, ws + OFF_VC);
    k_fused<<<dim3(64, 4), 512, 0, stream>>>(x, bmk, bmq, Wmv, ws);
    k_reduce<<<130, 256, 0, stream>>>(ws);
    k_out<<<dim3(64, 8), 256, 0, stream>>>(ws, out);
}

// Round 5
// 133.153 us; speedup vs baseline: 1.1138x; 1.0568x over previous
//
#include <hip/hip_runtime.h>
#include <math.h>

#define EPS_F 1e-6f

typedef __attribute__((ext_vector_type(8))) short bf16x8;
typedef __attribute__((ext_vector_type(4))) float f32x4;

// ---- workspace layout (float offsets) ----
#define OFF_BV  0                            // folded v bias [256]
#define OFF_VC  (OFF_BV + 256)               // dwconv output [256][4096]
#define OFF_PS  (OFF_VC + 256*4096)          // partial Sm [8 h][64 chunk][64][64]
#define OFF_PSV (OFF_PS + 8*64*4096)         // partial sv [8 h][64 chunk][64]
#define OFF_SM  (OFF_PSV + 8*64*64)          // Sm [8][64*64]
#define OFF_SV  (OFF_SM + 8*4096)            // sv [8][64]
#define OFF_QF  (OFF_SV + 512)               // qf [512 row=h*64+a][4096 n] fp32
#define OFF_WQH (OFF_QF + 512*4096)          // folded Wq hi bf16 [256][256] (ushort)
#define OFF_WQL (OFF_WQH + 32768)
#define OFF_WKH (OFF_WQL + 32768)
#define OFF_WKL (OFF_WKH + 32768)
#define OFF_XTH (OFF_WKL + 32768)            // X^T hi bf16 [4096 tok][256 c] (ushort)
#define OFF_XTL (OFF_XTH + 524288)

__device__ __forceinline__ void split_bf16(float v, unsigned short& h, unsigned short& l) {
    unsigned int b = __float_as_uint(v);
    h = (unsigned short)(b >> 16);
    float fh = __uint_as_float(b & 0xFFFF0000u);
    l = (unsigned short)(__float_as_uint(v - fh) >> 16);
}

// Fold hedgehog linear into 1x1x1 conv, emit split-bf16 weights:
// Wcq[h*64+e,c] = sum_d Wmq[e,d]*Wq[h*64+d,c]  -> (WQH,WQL); same for k.
__global__ __launch_bounds__(256) void k_combine(
    const float* __restrict__ Wq, const float* __restrict__ Wk,
    const float* __restrict__ Wmq, const float* __restrict__ Wmk,
    const float* __restrict__ Wmv, const float* __restrict__ bmv,
    const float* __restrict__ bv, float* __restrict__ ws)
{
    int row = blockIdx.x;        // h*64+e
    int c = threadIdx.x;
    int h = row >> 6, e = row & 63;
    float aq = 0.f, ak = 0.f;
    for (int d = 0; d < 64; ++d) {
        float mq = Wmq[e*64 + d];
        float mk = Wmk[e*64 + d];
        int src = (h*64 + d)*256 + c;
        aq = fmaf(mq, Wq[src], aq);
        ak = fmaf(mk, Wk[src], ak);
    }
    unsigned short hh, ll;
    unsigned short* WQH = (unsigned short*)(ws + OFF_WQH);
    unsigned short* WQL = (unsigned short*)(ws + OFF_WQL);
    unsigned short* WKH = (unsigned short*)(ws + OFF_WKH);
    unsigned short* WKL = (unsigned short*)(ws + OFF_WKL);
    split_bf16(aq, hh, ll); WQH[row*256 + c] = hh; WQL[row*256 + c] = ll;
    split_bf16(ak, hh, ll); WKH[row*256 + c] = hh; WKL[row*256 + c] = ll;
    if (c == 0) {
        float av = 0.f;
        for (int d = 0; d < 64; ++d) av = fmaf(Wmv[e*64 + d], bv[h*64 + d], av);
        ws[OFF_BV + row] = av + bmv[e];
    }
}

// Transpose + split X: x [256 c][4096 n] fp32 -> XT hi/lo bf16 [4096 tok][256 c]
__global__ __launch_bounds__(256) void k_xt(
    const float* __restrict__ x, float* __restrict__ ws)
{
    __shared__ float Ts[64][65];
    int tx = blockIdx.x;         // token tile 0..63
    int cy = blockIdx.y;         // c tile 0..3
    int t = threadIdx.x;
    int lr = t >> 6, lc2 = t & 63;
    #pragma unroll
    for (int i = 0; i < 16; ++i) {
        int row = lr*16 + i;
        Ts[row][lc2] = x[(size_t)(cy*64 + row)*4096 + tx*64 + lc2];
    }
    __syncthreads();
    int tok = t >> 2, c16 = (t & 3) * 16;
    unsigned int hw[8], lw[8];
    #pragma unroll
    for (int j = 0; j < 8; ++j) {
        float v0 = Ts[c16 + 2*j][tok], v1 = Ts[c16 + 2*j + 1][tok];
        unsigned int b0 = __float_as_uint(v0), b1 = __float_as_uint(v1);
        hw[j] = (b0 >> 16) | (b1 & 0xFFFF0000u);
        float f0 = __uint_as_float(b0 & 0xFFFF0000u);
        float f1 = __uint_as_float(b1 & 0xFFFF0000u);
        lw[j] = (__float_as_uint(v0 - f0) >> 16) | (__float_as_uint(v1 - f1) & 0xFFFF0000u);
    }
    unsigned short* XH = (unsigned short*)(ws + OFF_XTH);
    unsigned short* XL = (unsigned short*)(ws + OFF_XTL);
    size_t base = (size_t)(tx*64 + tok)*256 + cy*64 + c16;
    uint4 H0 = {hw[0], hw[1], hw[2], hw[3]}, H1 = {hw[4], hw[5], hw[6], hw[7]};
    uint4 L0 = {lw[0], lw[1], lw[2], lw[3]}, L1 = {lw[4], lw[5], lw[6], lw[7]};
    *(uint4*)(XH + base) = H0;  *(uint4*)(XH + base + 8) = H1;
    *(uint4*)(XL + base) = L0;  *(uint4*)(XL + base + 8) = L1;
}

// depthwise 3x3x3 conv, zero pad
__global__ __launch_bounds__(256) void k_dwconv(
    const float* __restrict__ x, const float* __restrict__ Wv, float* __restrict__ vc)
{
    int c = blockIdx.y;
    int n = blockIdx.x * 256 + threadIdx.x;
    int z = n >> 8, y = (n >> 4) & 15, xx = n & 15;
    const float* xc = x + c * 4096;
    const float* wc = Wv + c * 27;
    float acc = 0.f;
    #pragma unroll
    for (int kz = 0; kz < 3; ++kz) {
        int zz = z + kz - 1;
        if (zz < 0 || zz > 15) continue;
        #pragma unroll
        for (int ky = 0; ky < 3; ++ky) {
            int yy = y + ky - 1;
            if (yy < 0 || yy > 15) continue;
            #pragma unroll
            for (int kx = 0; kx < 3; ++kx) {
                int xv = xx + kx - 1;
                if (xv < 0 || xv > 15) continue;
                acc = fmaf(wc[(kz*3 + ky)*3 + kx], xc[(zz << 8) + (yy << 4) + xv], acc);
            }
        }
    }
    vc[c*4096 + n] = acc;
}

// 512 threads / 8 waves. Phase 1: K & Q projections (K=256) via split-bf16 MFMA
// (wave roles: kq=w>>2 selects K/Q, mh=w&1 token-half, nh=(w>>1)&1 feat-half;
//  assumed frag layout: A row=l&15,k=(l>>4)*8+j ; B col=l&15, same k ; D per m89).
// Then: V-proj (K=64, scalar), exp into LDS, outer products (scalar, n-split),
// exchange, PS/PSV writes; finally Q-waves emit qf via LDS transpose (old layout).
__global__ __launch_bounds__(512, 2) void k_fused(
    const float* __restrict__ bmk, const float* __restrict__ bmq,
    const float* __restrict__ Wmv, float* __restrict__ ws)
{
    __shared__ float smem[16384];   // 64 KB
    unsigned short* su = (unsigned short*)smem;

    int t = threadIdx.x;
    int chunk = blockIdx.x;       // 0..63
    int hb = blockIdx.y;          // 0..3
    int n0 = chunk * 64;
    int w = t >> 6, lane = t & 63;
    int kq = w >> 2;              // 0 = K waves (t<256), 1 = Q waves
    int mh = w & 1, nh = (w >> 1) & 1;
    int l15 = lane & 15, l4 = lane >> 4;
    bool isQ = (t >= 256);
    int tl = t & 255;
    int lc = tl >> 6, ln = tl & 63;
    int e4 = (tl & 15) * 4;
    int n4 = (tl >> 4) * 4;

    const unsigned short* XH  = (const unsigned short*)(ws + OFF_XTH);
    const unsigned short* XL  = (const unsigned short*)(ws + OFF_XTL);
    const unsigned short* WKHp = (const unsigned short*)(ws + OFF_WKH);
    const unsigned short* WKLp = (const unsigned short*)(ws + OFF_WKL);
    const unsigned short* WQHp = (const unsigned short*)(ws + OFF_WQH);
    const unsigned short* WQLp = (const unsigned short*)(ws + OFF_WQL);

    f32x4 acc[2][2];
    #pragma unroll
    for (int i = 0; i < 2; ++i)
        #pragma unroll
        for (int j = 0; j < 2; ++j) acc[i][j] = (f32x4){0.f, 0.f, 0.f, 0.f};
    float accV[4][4];
    #pragma unroll
    for (int i = 0; i < 4; ++i)
        #pragma unroll
        for (int j = 0; j < 4; ++j) accV[i][j] = 0.f;

    // ---- phase 1: K & Q projection GEMMs via MFMA, 4 slabs of K=64 ----
    for (int cs = 0; cs < 4; ++cs) {
        int c0 = cs * 64;
        {   // stage 6 x [64 rows][64 c] bf16 buffers, XOR-swizzled 16B slots
            int r = (t >> 3) & 63, s = t & 7;
            unsigned short* d = su + r*64 + (((s ^ (r & 7))) << 3);
            size_t xo = (size_t)(n0 + r)*256 + c0 + s*8;
            size_t wo = (size_t)(hb*64 + r)*256 + c0 + s*8;
            *(uint4*)(d)         = *(const uint4*)(XH + xo);
            *(uint4*)(d + 4096)  = *(const uint4*)(XL + xo);
            *(uint4*)(d + 8192)  = *(const uint4*)(WKHp + wo);
            *(uint4*)(d + 12288) = *(const uint4*)(WKLp + wo);
            *(uint4*)(d + 16384) = *(const uint4*)(WQHp + wo);
            *(uint4*)(d + 20480) = *(const uint4*)(WQLp + wo);
        }
        __syncthreads();
        const unsigned short* Xh = su;
        const unsigned short* Xl = su + 4096;
        const unsigned short* Wh = su + 8192 + kq*8192;
        const unsigned short* Wl = Wh + 4096;
        #pragma unroll
        for (int ks = 0; ks < 2; ++ks) {
            bf16x8 ah[2], al[2], bh_[2], bl_[2];
            #pragma unroll
            for (int mt = 0; mt < 2; ++mt) {
                int ar = mh*32 + mt*16 + l15;
                int off = ar*64 + (((ks*4 + l4) ^ (ar & 7)) << 3);
                ah[mt] = *(const bf16x8*)(Xh + off);
                al[mt] = *(const bf16x8*)(Xl + off);
            }
            #pragma unroll
            for (int nt = 0; nt < 2; ++nt) {
                int br = nh*32 + nt*16 + l15;
                int off = br*64 + (((ks*4 + l4) ^ (br & 7)) << 3);
                bh_[nt] = *(const bf16x8*)(Wh + off);
                bl_[nt] = *(const bf16x8*)(Wl + off);
            }
            #pragma unroll
            for (int mt = 0; mt < 2; ++mt)
                #pragma unroll
                for (int nt = 0; nt < 2; ++nt) {
                    acc[mt][nt] = __builtin_amdgcn_mfma_f32_16x16x32_bf16(ah[mt], bh_[nt], acc[mt][nt], 0, 0, 0);
                    acc[mt][nt] = __builtin_amdgcn_mfma_f32_16x16x32_bf16(al[mt], bh_[nt], acc[mt][nt], 0, 0, 0);
                    acc[mt][nt] = __builtin_amdgcn_mfma_f32_16x16x32_bf16(ah[mt], bl_[nt], acc[mt][nt], 0, 0, 0);
                }
        }
        __syncthreads();
    }

    // ---- K waves stage V tiles (VC + Wmv) ----
    float (*Xs)[64]  = (float(*)[64])smem;            // VC tile
    float (*Wsh)[68] = (float(*)[68])(smem + 4096);   // Wmv
    if (!isQ) {
        const float* vcb = ws + OFF_VC + (size_t)hb*64*4096;
        #pragma unroll
        for (int i = 0; i < 16; ++i)
            Xs[lc*16 + i][ln] = vcb[(size_t)(lc*16 + i)*4096 + n0 + ln];
        #pragma unroll
        for (int i = 0; i < 16; ++i) { int idx = i*256 + tl; Wsh[idx & 63][idx >> 6] = Wmv[idx]; }
    }
    __syncthreads();

    // ---- V-projection GEMM (K waves, scalar, K=64) ----
    if (!isQ) {
        #pragma unroll 4
        for (int d = 0; d < 64; ++d) {
            float4 xv4 = *(const float4*)&Xs[d][n4];
            float4 wv4 = *(const float4*)&Wsh[d][e4];
            float xv[4] = {xv4.x, xv4.y, xv4.z, xv4.w};
            float wv[4] = {wv4.x, wv4.y, wv4.z, wv4.w};
            #pragma unroll
            for (int ii = 0; ii < 4; ++ii)
                #pragma unroll
                for (int jj = 0; jj < 4; ++jj)
                    accV[ii][jj] = fmaf(xv[ii], wv[jj], accV[ii][jj]);
        }
    }
    __syncthreads();

    // ---- phase 2: K waves write kf (from MFMA D-frags) and vf (scalar) ----
    float (*kfp)[64] = (float(*)[64])smem;
    float (*kfm)[64] = (float(*)[64])(smem + 4096);
    float (*vfp)[64] = (float(*)[64])(smem + 8192);
    float (*vfm)[64] = (float(*)[64])(smem + 12288);
    if (!isQ) {
        float bk0 = bmk[nh*32 + l15], bk1 = bmk[nh*32 + 16 + l15];
        #pragma unroll
        for (int mt = 0; mt < 2; ++mt)
            #pragma unroll
            for (int nt = 0; nt < 2; ++nt) {
                float bkv = nt ? bk1 : bk0;
                int feat = nh*32 + nt*16 + l15;
                #pragma unroll
                for (int r = 0; r < 4; ++r) {
                    int tok = mh*32 + mt*16 + l4*4 + r;
                    float v = acc[mt][nt][r] + bkv;
                    kfp[tok][feat] = __expf(v);
                    kfm[tok][feat] = __expf(-v);
                }
            }
        float bvv[4];
        #pragma unroll
        for (int j = 0; j < 4; ++j) bvv[j] = ws[OFF_BV + hb*64 + e4 + j];
        #pragma unroll
        for (int ii = 0; ii < 4; ++ii) {
            float pv[4], mv[4];
            #pragma unroll
            for (int jj = 0; jj < 4; ++jj) {
                float b = accV[ii][jj] + bvv[jj];
                pv[jj] = __expf(b);  mv[jj] = __expf(-b);
            }
            *(float4*)&vfp[n4 + ii][e4] = make_float4(pv[0], pv[1], pv[2], pv[3]);
            *(float4*)&vfm[n4 + ii][e4] = make_float4(mv[0], mv[1], mv[2], mv[3]);
        }
    }
    __syncthreads();

    // ---- phase 3: outer products, n-split across groups (scalar) ----
    float aSp[4][4], aSm[4][4], svp[4], svm[4];
    #pragma unroll
    for (int i = 0; i < 4; ++i) {
        svp[i] = 0.f; svm[i] = 0.f;
        #pragma unroll
        for (int j = 0; j < 4; ++j) { aSp[i][j] = 0.f; aSm[i][j] = 0.f; }
    }
    int a4 = e4, f4 = n4;
    int nb = isQ ? 32 : 0;
    #pragma unroll 2
    for (int nn = 0; nn < 32; ++nn) {
        int n = nb + nn;
        float4 kp4 = *(const float4*)&kfp[n][a4];
        float4 km4 = *(const float4*)&kfm[n][a4];
        float4 vp4 = *(const float4*)&vfp[n][f4];
        float4 vm4 = *(const float4*)&vfm[n][f4];
        float kp[4] = {kp4.x, kp4.y, kp4.z, kp4.w};
        float km[4] = {km4.x, km4.y, km4.z, km4.w};
        float vp[4] = {vp4.x, vp4.y, vp4.z, vp4.w};
        float vm[4] = {vm4.x, vm4.y, vm4.z, vm4.w};
        #pragma unroll
        for (int ai = 0; ai < 4; ++ai) {
            svp[ai] += kp[ai];  svm[ai] += km[ai];
            #pragma unroll
            for (int fi = 0; fi < 4; ++fi) {
                aSp[ai][fi] = fmaf(kp[ai], vp[fi], aSp[ai][fi]);
                aSm[ai][fi] = fmaf(km[ai], vm[fi], aSm[ai][fi]);
            }
        }
    }
    __syncthreads();

    // ---- exchange: Q dumps partials, K adds and writes PS/PSV ----
    if (isQ) {
        #pragma unroll
        for (int i = 0; i < 4; ++i)
            #pragma unroll
            for (int j = 0; j < 4; ++j) {
                smem[(i*4 + j)*256 + tl]      = aSp[i][j];
                smem[(16 + i*4 + j)*256 + tl] = aSm[i][j];
            }
        if (tl < 16) {
            #pragma unroll
            for (int i = 0; i < 4; ++i) {
                smem[8192 + i*16 + tl]      = svp[i];
                smem[8192 + 64 + i*16 + tl] = svm[i];
            }
        }
    }
    __syncthreads();
    if (!isQ) {
        #pragma unroll
        for (int i = 0; i < 4; ++i)
            #pragma unroll
            for (int j = 0; j < 4; ++j) {
                aSp[i][j] += smem[(i*4 + j)*256 + tl];
                aSm[i][j] += smem[(16 + i*4 + j)*256 + tl];
            }
        float* pSp = ws + OFF_PS + (size_t)(hb*64 + chunk)*4096;
        float* pSm = ws + OFF_PS + (size_t)((hb + 4)*64 + chunk)*4096;
        #pragma unroll
        for (int ai = 0; ai < 4; ++ai) {
            *(float4*)&pSp[(a4 + ai)*64 + f4] = make_float4(aSp[ai][0], aSp[ai][1], aSp[ai][2], aSp[ai][3]);
            *(float4*)&pSm[(a4 + ai)*64 + f4] = make_float4(aSm[ai][0], aSm[ai][1], aSm[ai][2], aSm[ai][3]);
        }
        if (tl < 16) {
            #pragma unroll
            for (int i = 0; i < 4; ++i) {
                svp[i] += smem[8192 + i*16 + tl];
                svm[i] += smem[8192 + 64 + i*16 + tl];
            }
            float* pvp = ws + OFF_PSV + (size_t)(hb*64 + chunk)*64;
            float* pvm = ws + OFF_PSV + (size_t)((hb + 4)*64 + chunk)*64;
            *(float4*)&pvp[a4] = make_float4(svp[0], svp[1], svp[2], svp[3]);
            *(float4*)&pvm[a4] = make_float4(svm[0], svm[1], svm[2], svm[3]);
        }
    }
    __syncthreads();

    // ---- Q waves: exp(+-q) from D-frags -> LDS transpose [feat][tok] ----
    float (*qTp)[68] = (float(*)[68])smem;            // [64][68]
    float (*qTm)[68] = (float(*)[68])(smem + 4352);
    if (isQ) {
        float bq0 = bmq[nh*32 + l15], bq1 = bmq[nh*32 + 16 + l15];
        #pragma unroll
        for (int mt = 0; mt < 2; ++mt)
            #pragma unroll
            for (int nt = 0; nt < 2; ++nt) {
                float bqv = nt ? bq1 : bq0;
                int feat = nh*32 + nt*16 + l15;
                #pragma unroll
                for (int r = 0; r < 4; ++r) {
                    int tok = mh*32 + mt*16 + l4*4 + r;
                    float v = acc[mt][nt][r] + bqv;
                    qTp[feat][tok] = __expf(v);
                    qTm[feat][tok] = __expf(-v);
                }
            }
    }
    __syncthreads();
    // ---- all threads: copy qT -> global qf (old feature-major layout) ----
    float* gq = ws + OFF_QF;
    #pragma unroll
    for (int j = 0; j < 4; ++j) {
        int un = t + 512*j;               // 0..2047
        int s = un >> 10;
        int rem = un & 1023;
        int feat = rem >> 4, t4 = (rem & 15) * 4;
        const float* src = (s ? &qTm[feat][t4] : &qTp[feat][t4]);
        float4 v = *(const float4*)src;
        *(float4*)&gq[(size_t)((hb + 4*s)*64 + feat)*4096 + n0 + t4] = v;
    }
}

__global__ __launch_bounds__(256) void k_reduce(float* __restrict__ ws)
{
    int idx = blockIdx.x*256 + threadIdx.x;
    if (idx < 8*4096) {
        int h = idx >> 12, r = idx & 4095;
        float s = 0.f;
        #pragma unroll 16
        for (int c = 0; c < 64; ++c) s += ws[OFF_PS + (size_t)(h*64 + c)*4096 + r];
        ws[OFF_SM + idx] = s;
    } else if (idx < 8*4096 + 512) {
        int j = idx - 8*4096;
        int h = j >> 6, e = j & 63;
        float s = 0.f;
        #pragma unroll 16
        for (int c = 0; c < 64; ++c) s += ws[OFF_PSV + (size_t)(h*64 + c)*64 + e];
        ws[OFF_SV + j] = s;
    }
}

// Per (h 0..7, chunk 0..63): out[h] = (qf[h] . Sm[h]) / (qf[h] . sv[h] + eps)
__global__ __launch_bounds__(256, 2) void k_out(
    const float* __restrict__ ws, float* __restrict__ out)
{
    __shared__ float qs[64][64];    // qf tile [a][n]
    __shared__ float Sms[64][64];   // Sm[h]   [a][f]
    __shared__ float svs[64];
    int t = threadIdx.x;
    int chunk = blockIdx.x;
    int h = blockIdx.y;
    int n0 = chunk * 64;
    int lc = t >> 6, ln = t & 63;

    const float* gq = ws + OFF_QF + (size_t)h*64*4096;
    #pragma unroll
    for (int i = 0; i < 16; ++i)
        qs[lc*16 + i][ln] = gq[(size_t)(lc*16 + i)*4096 + n0 + ln];
    const float* Smg = ws + OFF_SM + (size_t)h*4096;
    #pragma unroll
    for (int i = 0; i < 16; ++i) { int idx = i*256 + t; Sms[idx >> 6][idx & 63] = Smg[idx]; }
    if (t < 64) svs[t] = ws[OFF_SV + h*64 + t];
    __syncthreads();

    int n4 = (t & 15) * 4;
    int e4 = (t >> 4) * 4;
    float acc[4][4];                // [f][n]
    float den[4] = {0.f, 0.f, 0.f, 0.f};
    #pragma unroll
    for (int i = 0; i < 4; ++i)
        #pragma unroll
        for (int j = 0; j < 4; ++j) acc[i][j] = 0.f;
    #pragma unroll 4
    for (int a = 0; a < 64; ++a) {
        float4 qv4 = *(const float4*)&qs[a][n4];
        float4 sm4 = *(const float4*)&Sms[a][e4];
        float qv[4] = {qv4.x, qv4.y, qv4.z, qv4.w};
        float sm[4] = {sm4.x, sm4.y, sm4.z, sm4.w};
        float sva = svs[a];
        #pragma unroll
        for (int nj = 0; nj < 4; ++nj) {
            den[nj] = fmaf(qv[nj], sva, den[nj]);
            #pragma unroll
            for (int ei = 0; ei < 4; ++ei)
                acc[ei][nj] = fmaf(sm[ei], qv[nj], acc[ei][nj]);
        }
    }
    float r[4];
    #pragma unroll
    for (int nj = 0; nj < 4; ++nj) r[nj] = 1.f / (den[nj] + EPS_F);
    #pragma unroll
    for (int ei = 0; ei < 4; ++ei)
        *(float4*)&out[(size_t)(h*64 + e4 + ei)*4096 + n0 + n4] =
            make_float4(acc[ei][0]*r[0], acc[ei][1]*r[1], acc[ei][2]*r[2], acc[ei][3]*r[3]);
}

extern "C" void kernel_launch(void* const* d_in, const int* in_sizes, int n_in,
                              void* d_out, int out_size, void* d_ws, size_t ws_size,
                              hipStream_t stream) {
    const float* x   = (const float*)d_in[0];
    const float* Wq  = (const float*)d_in[1];
    const float* Wk  = (const float*)d_in[2];
    const float* Wv  = (const float*)d_in[3];
    const float* bv  = (const float*)d_in[4];
    const float* Wmq = (const float*)d_in[5];
    const float* bmq = (const float*)d_in[6];
    const float* Wmk = (const float*)d_in[7];
    const float* bmk = (const float*)d_in[8];
    const float* Wmv = (const float*)d_in[9];
    const float* bmv = (const float*)d_in[10];
    float* out = (float*)d_out;
    float* ws  = (float*)d_ws;

    k_combine<<<256, 256, 0, stream>>>(Wq, Wk, Wmq, Wmk, Wmv, bmv, bv, ws);
    k_xt<<<dim3(64, 4), 256, 0, stream>>>(x, ws);
    k_dwconv<<<dim3(16, 256), 256, 0, stream>>>(x, Wv, ws + OFF_VC);
    k_fused<<<dim3(64, 4), 512, 0, stream>>>(bmk, bmq, Wmv, ws);
    k_reduce<<<130, 256, 0, stream>>>(ws);
    k_out<<<dim3(64, 8), 256, 0, stream>>>(ws, out);
}